// Round 19
// baseline (48.036 us; speedup 1.0000x reference)
//
#include <hip/hip_runtime.h>
#include <hip/hip_fp16.h>

// SSIM loss — round 19: fused direct-global h-MFMA (no prep, no sIn).
// Per (rt,ct) position: 4 float4 global loads (a,b) -> f16 fragments
// {a, b, aa+bb, ab} built in registers -> 4 MFMAs sharing loads + Ah band
// -> sV stores. 256 threads (4 waves): 12 h-positions = 3/wave, 8
// v-positions = 2/wave (both Av bands). One barrier in the main path.
// LDS 22.7KB -> 7 blocks/CU (28 waves). sV col-major VSTRIDE=44 (store-free
// banks). v-phase: 4xb32 reads + MFMA, lane-local SSIM, wave reduction.

#define IMGH 512
#define IMGW 512
#define TW 64
#define TH 32
#define GX 8
#define GY 16
#define GZ 48
#define NBLOCKS (GX * GY * GZ)   // 6144
#define NPIX (16 * 3 * 512 * 512)
#define C1F 1.0e-4f
#define C2F 9.0e-4f

#define VSTRIDE 44         // halfs/col (88B): h-store lane-groups disjoint
#define VPLANE (64 * VSTRIDE)
#define WBASE 34

// Gaussian weights, sigma=1.5, ws=11 (validated r1-r18).
#define W0 0.0010283818f
#define W1 0.0075987503f
#define W2 0.0360007547f
#define W3 0.1093606960f
#define W4 0.2130055367f
#define W5 0.2660117184f

typedef _Float16 half8v __attribute__((ext_vector_type(8)));
typedef float f32x4 __attribute__((ext_vector_type(4)));
union H8 { half8v v; __half2 h2[4]; float4 f4; unsigned u[4]; };

static __device__ __forceinline__ __half2 pkrtz(float a, float b) {
    auto r = __builtin_amdgcn_cvt_pkrtz(a, b);   // __fp16 ext_vector(2)
    return *reinterpret_cast<__half2*>(&r);
}

__global__ __launch_bounds__(256, 7)
void ssim_tile(const float* __restrict__ img1, const float* __restrict__ img2,
               float* __restrict__ partials) {
    __shared__ _Float16 sWext[96];          // [WBASE..WBASE+10] = W[0..10]
    __shared__ _Float16 sV[4 * VPLANE];     // 22,528 B : col-major, 44 rows
    __shared__ float wsum[4];

    const int tid  = threadIdx.x;
    const int lane = tid & 63;
    const int wv   = tid >> 6;              // 0..3
    const int lr = lane & 15;               // row-in-tile / out-col lane
    const int kc = lane >> 4;               // K-chunk 0..3
    const int r0 = blockIdx.y * TH;
    const int c0 = blockIdx.x * TW;
    const size_t pbase = (size_t)blockIdx.z * (IMGH * IMGW);
    const float* a0 = img1 + pbase;
    const float* b0 = img2 + pbase;
    const bool fast = (blockIdx.x >= 1) & (blockIdx.x <= GX - 2) &
                      (blockIdx.y >= 1) & (blockIdx.y <= GY - 2);

    // ---- weight table, then tiny barrier (nothing else pending) ----
    if (tid < 96) {
        const float W[11] = {W0, W1, W2, W3, W4, W5, W4, W3, W2, W1, W0};
        float w = 0.f;
#pragma unroll
        for (int j = 0; j < 11; ++j) w = (tid == WBASE + j) ? W[j] : w;
        sWext[tid] = (_Float16)w;
    }
    __syncthreads();

    // ---- A fragments (m89 layout: M=lane&15, K=(lane>>4)*8+e) ----
    half8v Ah, Av0, Av1;
    {
        const int b0i = (kc << 3) - lr + WBASE;
#pragma unroll
        for (int e = 0; e < 8; ++e) Ah[e]  = sWext[b0i - 3 + e];  // W[k-m-3]
#pragma unroll
        for (int e = 0; e < 8; ++e) Av0[e] = sWext[b0i + e];      // W[k-m]
#pragma unroll
        for (int e = 0; e < 8; ++e) Av1[e] = sWext[b0i - 6 + e];  // W[k-m-6]
    }

    // ---- h-phase: wave wv = col-chunk ct; 3 row-tiles; 4 q per tile ----
    {
        const int ct = wv;
        const int gcb = c0 - 8 + 16 * ct + (kc << 3);   // 8 f32: gcb..gcb+7
#pragma unroll
        for (int rt = 0; rt < 3; ++rt) {
            const int rb = (rt == 0) ? 0 : (rt == 1 ? 16 : 26);
            const int row = rb + lr;                    // staged row 0..41
            const int gr = r0 - 5 + row;
            float4 va1, va2, vb1, vb2;
            if (fast) {
                const float* pa = a0 + (size_t)gr * IMGW + gcb;
                const float* pb = b0 + (size_t)gr * IMGW + gcb;
                va1 = *reinterpret_cast<const float4*>(pa);
                va2 = *reinterpret_cast<const float4*>(pa + 4);
                vb1 = *reinterpret_cast<const float4*>(pb);
                vb2 = *reinterpret_cast<const float4*>(pb + 4);
            } else {
                const float4 z = make_float4(0.f, 0.f, 0.f, 0.f);
                const bool okr = (unsigned)gr < IMGH;
                const bool ok1 = okr & ((unsigned)gcb < IMGW);
                const bool ok2 = okr & ((unsigned)(gcb + 4) < IMGW);
                const int grc = okr ? gr : 0;
                const int g1 = ok1 ? gcb : 0;
                const int g2 = ok2 ? gcb + 4 : 4;
                const float* pa = a0 + (size_t)grc * IMGW;
                const float* pb = b0 + (size_t)grc * IMGW;
                float4 t;
                t = *reinterpret_cast<const float4*>(pa + g1); va1 = ok1 ? t : z;
                t = *reinterpret_cast<const float4*>(pa + g2); va2 = ok2 ? t : z;
                t = *reinterpret_cast<const float4*>(pb + g1); vb1 = ok1 ? t : z;
                t = *reinterpret_cast<const float4*>(pb + g2); vb2 = ok2 ? t : z;
            }
            H8 fa, fb, fq, fc;
            fa.h2[0] = pkrtz(va1.x, va1.y); fa.h2[1] = pkrtz(va1.z, va1.w);
            fa.h2[2] = pkrtz(va2.x, va2.y); fa.h2[3] = pkrtz(va2.z, va2.w);
            fb.h2[0] = pkrtz(vb1.x, vb1.y); fb.h2[1] = pkrtz(vb1.z, vb1.w);
            fb.h2[2] = pkrtz(vb2.x, vb2.y); fb.h2[3] = pkrtz(vb2.z, vb2.w);
#pragma unroll
            for (int t = 0; t < 4; ++t) {
                fq.h2[t] = __hfma2(fa.h2[t], fa.h2[t],
                                   __hmul2(fb.h2[t], fb.h2[t]));
                fc.h2[t] = __hmul2(fa.h2[t], fb.h2[t]);
            }
            f32x4 d0 = {0.f, 0.f, 0.f, 0.f}, d1 = d0, d2 = d0, d3 = d0;
            d0 = __builtin_amdgcn_mfma_f32_16x16x32_f16(Ah, fa.v, d0, 0, 0, 0);
            d1 = __builtin_amdgcn_mfma_f32_16x16x32_f16(Ah, fb.v, d1, 0, 0, 0);
            d2 = __builtin_amdgcn_mfma_f32_16x16x32_f16(Ah, fq.v, d2, 0, 0, 0);
            d3 = __builtin_amdgcn_mfma_f32_16x16x32_f16(Ah, fc.v, d3, 0, 0, 0);
#pragma unroll
            for (int j = 0; j < 4; ++j) {
                const int vb = (16 * ct + (kc << 2) + j) * VSTRIDE + row;
                sV[0 * VPLANE + vb] = (_Float16)d0[j];
                sV[1 * VPLANE + vb] = (_Float16)d1[j];
                sV[2 * VPLANE + vb] = (_Float16)d2[j];
                sV[3 * VPLANE + vb] = (_Float16)d3[j];
            }
        }
    }
    __syncthreads();

    // ---- v-phase: wave wv = ct2; rt2 = 0,1 (bands Av0/Av1); SSIM ----
    float lsum = 0.f;
    const int vcol = 16 * wv + lr;                      // out col (N)
#pragma unroll
    for (int rt2 = 0; rt2 < 2; ++rt2) {
        const int rowst = (rt2 ? 10 : 0) + (kc << 3);
        const int vbase = vcol * VSTRIDE + rowst;
        const half8v Avx = rt2 ? Av1 : Av0;
        auto vread = [&](int q) -> half8v {
            const _Float16* p = &sV[q * VPLANE + vbase];
            H8 c;
            c.u[0] = *reinterpret_cast<const unsigned*>(p);
            c.u[1] = *reinterpret_cast<const unsigned*>(p + 2);
            c.u[2] = *reinterpret_cast<const unsigned*>(p + 4);
            c.u[3] = *reinterpret_cast<const unsigned*>(p + 6);
            return c.v;
        };
        f32x4 d0 = {0.f, 0.f, 0.f, 0.f}, d1 = d0, d2 = d0, d3 = d0;
        d0 = __builtin_amdgcn_mfma_f32_16x16x32_f16(Avx, vread(0), d0, 0, 0, 0);
        d1 = __builtin_amdgcn_mfma_f32_16x16x32_f16(Avx, vread(1), d1, 0, 0, 0);
        d2 = __builtin_amdgcn_mfma_f32_16x16x32_f16(Avx, vread(2), d2, 0, 0, 0);
        d3 = __builtin_amdgcn_mfma_f32_16x16x32_f16(Avx, vread(3), d3, 0, 0, 0);
#pragma unroll
        for (int r = 0; r < 4; ++r) {
            const float mu1 = d0[r], mu2 = d1[r], S = d2[r], eab = d3[r];
            const float mu11 = mu1 * mu1, mu22 = mu2 * mu2, mu12 = mu1 * mu2;
            const float s12 = eab - mu12;
            const float num = (2.f * mu12 + C1F) * (2.f * s12 + C2F);
            const float den = (mu11 + mu22 + C1F) * ((S - mu11 - mu22) + C2F);
            lsum += num * __builtin_amdgcn_rcpf(den);
        }
    }

    // ---- deterministic block reduction (4 waves) ----
#pragma unroll
    for (int off = 32; off > 0; off >>= 1) lsum += __shfl_down(lsum, off, 64);
    if (lane == 0) wsum[wv] = lsum;
    __syncthreads();
    if (tid == 0) {
        float t = wsum[0] + wsum[1] + wsum[2] + wsum[3];
        partials[((size_t)blockIdx.z * GY + blockIdx.y) * GX + blockIdx.x] = t;
    }
}

__global__ __launch_bounds__(1024)
void ssim_reduce(const float* __restrict__ partials, float* __restrict__ out, int n) {
    __shared__ float lds[1024];
    float s = 0.f;
    for (int i = threadIdx.x; i < n; i += 1024) s += partials[i];
    lds[threadIdx.x] = s;
    __syncthreads();
    for (int off = 512; off > 0; off >>= 1) {
        if ((int)threadIdx.x < off) lds[threadIdx.x] += lds[threadIdx.x + off];
        __syncthreads();
    }
    if (threadIdx.x == 0) out[0] = 1.f - lds[0] / (float)NPIX;
}

extern "C" void kernel_launch(void* const* d_in, const int* in_sizes, int n_in,
                              void* d_out, int out_size, void* d_ws, size_t ws_size,
                              hipStream_t stream) {
    const float* img1 = (const float*)d_in[0];
    const float* img2 = (const float*)d_in[1];
    float* out = (float*)d_out;
    float* partials = (float*)d_ws;

    dim3 grid(GX, GY, GZ);
    ssim_tile<<<grid, 256, 0, stream>>>(img1, img2, partials);
    ssim_reduce<<<1, 1024, 0, stream>>>(partials, out, NBLOCKS);
}

// Round 20
// 41.312 us; speedup vs baseline: 1.1628x; 1.1628x over previous
//
#include <hip/hip_runtime.h>
#include <hip/hip_fp16.h>

// SSIM loss — round 20: h-MFMA operand swap -> b64 h-stores.
// mfma(In, Wband, acc): D's M = image row -> lane holds 4 consecutive rows
// at one out-col = col-major sV order -> 1 ds_write_b64 per q (rt2: 2xb32).
// 24 half-positions (rt,ct,q-pair), 3/wave, fa/fb shared within pair.
// v-phase: windows {0,12} (rows 42,43 zeroed), 2xb64 reads, bands
// W[K-m] / W[K-m-4]. All LDS patterns <=2-way bank-verified.
// 512 thr, LDS 37.5KB -> 4 blocks/CU.

#define IMGH 512
#define IMGW 512
#define TW 64
#define TH 32
#define GX 8
#define GY 16
#define GZ 48
#define NBLOCKS (GX * GY * GZ)   // 6144
#define NPIX (16 * 3 * 512 * 512)
#define C1F 1.0e-4f
#define C2F 9.0e-4f

#define INSTRIDE 88        // halfs/row (176B, b128-aligned reads)
#define INPLANE (42 * INSTRIDE)
#define VSTRIDE 44         // halfs/col (88B); rows 42,43 zeroed for window 12
#define VPLANE (64 * VSTRIDE)
#define WBASE 34

// Gaussian weights, sigma=1.5, ws=11 (validated r1-r19).
#define W0 0.0010283818f
#define W1 0.0075987503f
#define W2 0.0360007547f
#define W3 0.1093606960f
#define W4 0.2130055367f
#define W5 0.2660117184f

typedef _Float16 half8v __attribute__((ext_vector_type(8)));
typedef float f32x4 __attribute__((ext_vector_type(4)));
union H8 { half8v v; __half2 h2[4]; float4 f4; unsigned u[4]; };

static __device__ __forceinline__ __half2 pkrtz(float a, float b) {
    auto r = __builtin_amdgcn_cvt_pkrtz(a, b);   // __fp16 ext_vector(2)
    return *reinterpret_cast<__half2*>(&r);
}

__global__ __launch_bounds__(512, 8)
void ssim_tile(const float* __restrict__ img1, const float* __restrict__ img2,
               float* __restrict__ partials) {
    __shared__ _Float16 sWext[96];          // [WBASE..WBASE+10] = W[0..10]
    __shared__ _Float16 sIn[2 * INPLANE];   // 14,784 B : a | b
    __shared__ _Float16 sV[4 * VPLANE];     // 22,528 B : col-major, 44 rows
    __shared__ float wsum[8];

    const int tid  = threadIdx.x;
    const int lane = tid & 63;
    const int wv   = tid >> 6;
    const int lr = lane & 15;
    const int kc = lane >> 4;
    const int r0 = blockIdx.y * TH;
    const int c0 = blockIdx.x * TW;
    const size_t pbase = (size_t)blockIdx.z * (IMGH * IMGW);
    const float* a0 = img1 + pbase;
    const float* b0 = img2 + pbase;
    const bool fast = (blockIdx.x >= 1) & (blockIdx.x <= GX - 2) &
                      (blockIdx.y >= 1) & (blockIdx.y <= GY - 2);

    // ---- weight table + zero sV rows 42,43 (v window 12..43 padding) ----
    if (tid < 96) {
        const float W[11] = {W0, W1, W2, W3, W4, W5, W4, W3, W2, W1, W0};
        float w = 0.f;
#pragma unroll
        for (int j = 0; j < 11; ++j) w = (tid == WBASE + j) ? W[j] : w;
        sWext[tid] = (_Float16)w;
    }
    if (tid < 256) {
        const int q = tid >> 6, col = tid & 63;
        *reinterpret_cast<unsigned*>(&sV[q * VPLANE + col * VSTRIDE + 42]) = 0u;
    }

    // ---- prep: 420 items (42 rows x 10 8-col chunks), 1/thread ----
    if (tid < 420) {
        const int row = (unsigned)tid / 10u;
        const int ch  = tid - row * 10;
        const int gr = r0 - 5 + row;
        const int gc = c0 - 8 + 8 * ch;
        float4 va1, va2, vb1, vb2;
        if (fast) {
            const float* pa = a0 + (size_t)gr * IMGW + gc;
            const float* pb = b0 + (size_t)gr * IMGW + gc;
            va1 = *reinterpret_cast<const float4*>(pa);
            va2 = *reinterpret_cast<const float4*>(pa + 4);
            vb1 = *reinterpret_cast<const float4*>(pb);
            vb2 = *reinterpret_cast<const float4*>(pb + 4);
        } else {
            va1 = make_float4(0.f, 0.f, 0.f, 0.f);
            va2 = vb1 = vb2 = va1;
            if ((unsigned)gr < IMGH && (unsigned)gc < IMGW) {
                const float* pa = a0 + (size_t)gr * IMGW + gc;
                const float* pb = b0 + (size_t)gr * IMGW + gc;
                va1 = *reinterpret_cast<const float4*>(pa);
                va2 = *reinterpret_cast<const float4*>(pa + 4);
                vb1 = *reinterpret_cast<const float4*>(pb);
                vb2 = *reinterpret_cast<const float4*>(pb + 4);
            }
        }
        const int off = row * INSTRIDE + 8 * ch;
        H8 ha, hb;
        ha.h2[0] = pkrtz(va1.x, va1.y); ha.h2[1] = pkrtz(va1.z, va1.w);
        ha.h2[2] = pkrtz(va2.x, va2.y); ha.h2[3] = pkrtz(va2.z, va2.w);
        hb.h2[0] = pkrtz(vb1.x, vb1.y); hb.h2[1] = pkrtz(vb1.z, vb1.w);
        hb.h2[2] = pkrtz(vb2.x, vb2.y); hb.h2[3] = pkrtz(vb2.z, vb2.w);
        *reinterpret_cast<float4*>(&sIn[off]) = ha.f4;
        *reinterpret_cast<float4*>(&sIn[INPLANE + off]) = hb.f4;
    }
    __syncthreads();

    // ---- weight fragments ----
    // h B-frag: W[K - n - 3], n = lr, K = 8kc+e.
    // v A-frags: window 0 -> W[K - m]; window 12 -> W[K - m - 4].
    half8v Wh, Av0, Av1;
    {
        const int bi = (kc << 3) - lr + WBASE;
#pragma unroll
        for (int e = 0; e < 8; ++e) Wh[e]  = sWext[bi - 3 + e];
#pragma unroll
        for (int e = 0; e < 8; ++e) Av0[e] = sWext[bi + e];
#pragma unroll
        for (int e = 0; e < 8; ++e) Av1[e] = sWext[bi - 4 + e];
    }

    // ---- h-phase: 24 half-positions (rt,ct,qp), 3 per wave ----
    // A-frag = input rows (M=lr), K along cols; D: lane = out-col 16ct+lr,
    // rows rb+4kc+j -> col-major b64 store (rt2: 2xb32, rb=26 is 4B-aligned).
    {
        const int ct = (wv >> 1) & 3;
        const int qp = wv & 1;
#pragma unroll
        for (int rt = 0; rt < 3; ++rt) {
            const int rb = (rt == 0) ? 0 : (rt == 1 ? 16 : 26);
            const int base = (rb + lr) * INSTRIDE + 16 * ct + (kc << 3);
            H8 fa, fb;
            fa.f4 = *reinterpret_cast<const float4*>(&sIn[base]);
            fb.f4 = *reinterpret_cast<const float4*>(&sIn[INPLANE + base]);
            H8 f0, f1;
            if (qp == 0) {
                f0 = fa; f1 = fb;
            } else {
#pragma unroll
                for (int t = 0; t < 4; ++t) {
                    f0.h2[t] = __hfma2(fa.h2[t], fa.h2[t],
                                       __hmul2(fb.h2[t], fb.h2[t]));
                    f1.h2[t] = __hmul2(fa.h2[t], fb.h2[t]);
                }
            }
            f32x4 d0 = {0.f, 0.f, 0.f, 0.f}, d1 = d0;
            d0 = __builtin_amdgcn_mfma_f32_16x16x32_f16(f0.v, Wh, d0, 0, 0, 0);
            d1 = __builtin_amdgcn_mfma_f32_16x16x32_f16(f1.v, Wh, d1, 0, 0, 0);
            const int p0 = qp * 2, p1 = qp * 2 + 1;
            const int vb = (16 * ct + lr) * VSTRIDE + rb + (kc << 2);
            uint2 s0, s1;
            __half2 h;
            h = pkrtz(d0[0], d0[1]); s0.x = *reinterpret_cast<unsigned*>(&h);
            h = pkrtz(d0[2], d0[3]); s0.y = *reinterpret_cast<unsigned*>(&h);
            h = pkrtz(d1[0], d1[1]); s1.x = *reinterpret_cast<unsigned*>(&h);
            h = pkrtz(d1[2], d1[3]); s1.y = *reinterpret_cast<unsigned*>(&h);
            if (rt < 2) {
                *reinterpret_cast<uint2*>(&sV[p0 * VPLANE + vb]) = s0;
                *reinterpret_cast<uint2*>(&sV[p1 * VPLANE + vb]) = s1;
            } else {     // rb=26: 4B-aligned only
                unsigned* q0 = reinterpret_cast<unsigned*>(&sV[p0 * VPLANE + vb]);
                unsigned* q1 = reinterpret_cast<unsigned*>(&sV[p1 * VPLANE + vb]);
                q0[0] = s0.x; q0[1] = s0.y;
                q1[0] = s1.x; q1[1] = s1.y;
            }
        }
    }
    __syncthreads();

    // ---- v-phase: wave wv: ct2 = wv&3, rt2 = wv>>2; 2xb64 reads ----
    float lsum = 0.f;
    {
        const int ct2 = wv & 3;
        const int rt2 = wv >> 2;
        const int w0 = rt2 ? 12 : 0;
        const half8v Avx = rt2 ? Av1 : Av0;
        const int vcol = 16 * ct2 + lr;
        const int vbase = vcol * VSTRIDE + w0 + (kc << 3);
        auto vread = [&](int q) -> half8v {
            const _Float16* p = &sV[q * VPLANE + vbase];
            H8 c;
            *reinterpret_cast<uint2*>(&c.u[0]) =
                *reinterpret_cast<const uint2*>(p);
            *reinterpret_cast<uint2*>(&c.u[2]) =
                *reinterpret_cast<const uint2*>(p + 4);
            return c.v;
        };
        f32x4 d0 = {0.f, 0.f, 0.f, 0.f}, d1 = d0, d2 = d0, d3 = d0;
        d0 = __builtin_amdgcn_mfma_f32_16x16x32_f16(Avx, vread(0), d0, 0, 0, 0);
        d1 = __builtin_amdgcn_mfma_f32_16x16x32_f16(Avx, vread(1), d1, 0, 0, 0);
        d2 = __builtin_amdgcn_mfma_f32_16x16x32_f16(Avx, vread(2), d2, 0, 0, 0);
        d3 = __builtin_amdgcn_mfma_f32_16x16x32_f16(Avx, vread(3), d3, 0, 0, 0);
#pragma unroll
        for (int r = 0; r < 4; ++r) {
            const float mu1 = d0[r], mu2 = d1[r], S = d2[r], eab = d3[r];
            const float mu11 = mu1 * mu1, mu22 = mu2 * mu2, mu12 = mu1 * mu2;
            const float s12 = eab - mu12;
            const float num = (2.f * mu12 + C1F) * (2.f * s12 + C2F);
            const float den = (mu11 + mu22 + C1F) * ((S - mu11 - mu22) + C2F);
            lsum += num * __builtin_amdgcn_rcpf(den);
        }
    }

    // ---- deterministic block reduction (8 waves) ----
#pragma unroll
    for (int off = 32; off > 0; off >>= 1) lsum += __shfl_down(lsum, off, 64);
    if (lane == 0) wsum[wv] = lsum;
    __syncthreads();
    if (tid == 0) {
        float t = 0.f;
#pragma unroll
        for (int w = 0; w < 8; ++w) t += wsum[w];
        partials[((size_t)blockIdx.z * GY + blockIdx.y) * GX + blockIdx.x] = t;
    }
}

__global__ __launch_bounds__(1024)
void ssim_reduce(const float* __restrict__ partials, float* __restrict__ out, int n) {
    __shared__ float lds[1024];
    float s = 0.f;
    for (int i = threadIdx.x; i < n; i += 1024) s += partials[i];
    lds[threadIdx.x] = s;
    __syncthreads();
    for (int off = 512; off > 0; off >>= 1) {
        if ((int)threadIdx.x < off) lds[threadIdx.x] += lds[threadIdx.x + off];
        __syncthreads();
    }
    if (threadIdx.x == 0) out[0] = 1.f - lds[0] / (float)NPIX;
}

extern "C" void kernel_launch(void* const* d_in, const int* in_sizes, int n_in,
                              void* d_out, int out_size, void* d_ws, size_t ws_size,
                              hipStream_t stream) {
    const float* img1 = (const float*)d_in[0];
    const float* img2 = (const float*)d_in[1];
    float* out = (float*)d_out;
    float* partials = (float*)d_ws;

    dim3 grid(GX, GY, GZ);
    ssim_tile<<<grid, 512, 0, stream>>>(img1, img2, partials);
    ssim_reduce<<<1, 1024, 0, stream>>>(partials, out, NBLOCKS);
}